// Round 3
// baseline (594.655 us; speedup 1.0000x reference)
//
#include <hip/hip_runtime.h>
#include <hip/hip_bf16.h>
#include <stdint.h>

#define NFRM 8
#define NPTS 4096
#define NBOX 128
#define NS   32
#define TT   4
#define BB   2
#define FEATC 99
#define OUT1OFF (BB*NBOX*TT*NS*5)   /* 163840 */

/* ---------------- K1: validity + packed f32 point arrays ---------------- */
__global__ void k_prep(const float* __restrict__ pts, const float* __restrict__ rois,
                       float4* __restrict__ spk, float2* __restrict__ epk)
{
    int f = blockIdx.x >> 4;
    int n = ((blockIdx.x & 15) << 8) | threadIdx.x;
    __shared__ float bqx[NBOX], bqy[NBOX], brv[NBOX];
    if (threadIdx.x < NBOX){
        const float* bp = rois + (size_t)(f*NBOX + threadIdx.x)*7;
        float bx=bp[0], by=bp[1], dx=bp[3], dy=bp[4];
        float hx=__fmul_rn(dx,0.5f), hy=__fmul_rn(dy,0.5f);
        float hd=sqrtf(__fadd_rn(__fmul_rn(hx,hx),__fmul_rn(hy,hy)));
        brv[threadIdx.x]=ceilf(__fdiv_rn(__fmul_rn(hd,1.1f),0.4f));
        bqx[threadIdx.x]=floorf(__fdiv_rn(__fsub_rn(bx,-75.2f),0.4f));
        bqy[threadIdx.x]=floorf(__fdiv_rn(__fsub_rn(by,-75.2f),0.4f));
    }
    __syncthreads();
    const float* pp = pts + (size_t)(f*NPTS+n)*5;
    float x=pp[0], y=pp[1], z=pp[2], it=pp[3], ts=pp[4];
    float cx=floorf(__fdiv_rn(__fsub_rn(x,-75.2f),0.4f));
    float cy=floorf(__fdiv_rn(__fsub_rn(y,-75.2f),0.4f));
    float v=0.f;
    for (int m=0;m<NBOX;m++)
        if (fabsf(bqx[m]-cx)<brv[m] && fabsf(bqy[m]-cy)<brv[m]){ v=1.f; break; }
    spk[f*NPTS+n]=make_float4(x,y,z,v);
    epk[f*NPTS+n]=make_float2(it,ts);
}

/* ---------------- K2: ball-group + MLP + maxpool -> feats[32768][99] ---- */
/* LDS weight layout offsets (floats) */
#define W00 0
#define B00 80
#define W01 96
#define B01 352
#define W02 368
#define B02 880
#define W10 912
#define B10 1072
#define W11 1104
#define B11 2128
#define W12 2160
#define B12 4208
#define SWTOT 4272

__global__ __launch_bounds__(256) void k_feats(
    const float4* __restrict__ spk, const float2* __restrict__ epk,
    float* __restrict__ feats,
    const float* __restrict__ w00,const float* __restrict__ b00,
    const float* __restrict__ w01,const float* __restrict__ b01,
    const float* __restrict__ w02,const float* __restrict__ b02,
    const float* __restrict__ w10,const float* __restrict__ b10,
    const float* __restrict__ w11,const float* __restrict__ b11,
    const float* __restrict__ w12,const float* __restrict__ b12)
{
    __shared__ float sw[SWTOT];
    __shared__ int   lists[4][48];   /* per wave: [0..15]=r1 list, [16..47]=r2 list */
    int tid = threadIdx.x;
    {
        const float* srcs[12] = {w00,b00,w01,b01,w02,b02,w10,b10,w11,b11,w12,b12};
        const int offs[12]   = {W00,B00,W01,B01,W02,B02,W10,B10,W11,B11,W12,B12};
        const int cnts[12]   = {80,16,256,16,512,32,160,32,1024,32,2048,64};
        for (int a=0;a<12;a++)
            for (int i=tid;i<cnts[a];i+=256) sw[offs[a]+i]=srcs[a][i];
    }
    __syncthreads();

    int wv = tid >> 6, lane = tid & 63;
    int gp = (blockIdx.x << 2) | wv;         /* 0..32767 */
    int f = gp >> 12, n = gp & (NPTS-1);
    const float4* fsp = spk + f*NPTS;
    const float2* fep = epk + f*NPTS;
    float4 me = fsp[n];
    float sa = __fadd_rn(__fadd_rn(__fmul_rn(me.x,me.x),__fmul_rn(me.y,me.y)),__fmul_rn(me.z,me.z));
    const float RR1 = (float)(0.8*0.8);
    const float RR2 = (float)(1.6*1.6);
    int cnt1=0, cnt2=0;
    int* l1 = lists[wv];
    int* l2 = lists[wv]+16;
    uint64_t below = (1ull<<lane)-1ull;
    for (int j0=0;j0<NPTS;j0+=64){
        int j = j0 + lane;
        float4 q = fsp[j];
        float sb  = __fadd_rn(__fadd_rn(__fmul_rn(q.x,q.x),__fmul_rn(q.y,q.y)),__fmul_rn(q.z,q.z));
        float dot = __fadd_rn(__fadd_rn(__fmul_rn(me.x,q.x),__fmul_rn(me.y,q.y)),__fmul_rn(me.z,q.z));
        float d2 = fmaxf(__fsub_rn(__fadd_rn(sa,sb),__fmul_rn(2.0f,dot)), 0.f);
        bool vj = q.w > 0.5f;
        bool p1 = (d2 < RR1) && vj;
        bool p2 = (d2 < RR2) && vj;
        uint64_t m1 = __ballot(p1), m2 = __ballot(p2);
        if (p1){ int pos = cnt1 + __popcll(m1 & below); if (pos < 16) l1[pos] = j; }
        if (p2){ int pos = cnt2 + __popcll(m2 & below); if (pos < 32) l2[pos] = j; }
        cnt1 += __popcll(m1); cnt2 += __popcll(m2);
        if (cnt1 >= 16 && cnt2 >= 32) break;
    }
    cnt1 = min(cnt1,16); cnt2 = min(cnt2,32);
    __syncthreads();

    float* fo = feats + (size_t)gp*FEATC;

    /* ---- MLP0: 16 neighbors, 5->16->16->32, maxpool ---- */
    {
        int k = lane & 15;
        int idx = (k < cnt1) ? l1[k] : ((cnt1>0) ? l1[0] : 0);
        float4 q = fsp[idx]; float2 e = fep[idx];
        float g0=__fsub_rn(q.x,me.x), g1=__fsub_rn(q.y,me.y), g2=__fsub_rn(q.z,me.z);
        float g3=e.x, g4=e.y;
        float h1[16];
        #pragma unroll
        for (int o=0;o<16;o++){
            float a = sw[B00+o];
            a += g0*sw[W00+o*5+0]; a += g1*sw[W00+o*5+1]; a += g2*sw[W00+o*5+2];
            a += g3*sw[W00+o*5+3]; a += g4*sw[W00+o*5+4];
            h1[o] = fmaxf(a,0.f);
        }
        float h2[16];
        #pragma unroll
        for (int o=0;o<16;o++){
            float a = sw[B01+o];
            #pragma unroll
            for (int c=0;c<16;c++) a += h1[c]*sw[W01+o*16+c];
            h2[o] = fmaxf(a,0.f);
        }
        float h3[32];
        #pragma unroll
        for (int o=0;o<32;o++){
            float a = sw[B02+o];
            #pragma unroll
            for (int c=0;c<16;c++) a += h2[c]*sw[W02+o*16+c];
            h3[o] = fmaxf(a,0.f);
        }
        #pragma unroll
        for (int s=1;s<16;s<<=1){
            #pragma unroll
            for (int c=0;c<32;c++) h3[c] = fmaxf(h3[c], __shfl_xor(h3[c], s));
        }
        if (lane==0){
            fo[0]=me.x; fo[1]=me.y; fo[2]=me.z;
            #pragma unroll
            for (int c=0;c<32;c++) fo[3+c]=h3[c];
        }
    }

    /* ---- MLP1: 32 neighbors, 5->32->32->64, maxpool ---- */
    {
        int k = lane & 31;
        int idx = (k < cnt2) ? l2[k] : ((cnt2>0) ? l2[0] : 0);
        float4 q = fsp[idx]; float2 e = fep[idx];
        float g0=__fsub_rn(q.x,me.x), g1=__fsub_rn(q.y,me.y), g2=__fsub_rn(q.z,me.z);
        float g3=e.x, g4=e.y;
        float h1[32];
        #pragma unroll
        for (int o=0;o<32;o++){
            float a = sw[B10+o];
            a += g0*sw[W10+o*5+0]; a += g1*sw[W10+o*5+1]; a += g2*sw[W10+o*5+2];
            a += g3*sw[W10+o*5+3]; a += g4*sw[W10+o*5+4];
            h1[o] = fmaxf(a,0.f);
        }
        float h2[32];
        #pragma unroll
        for (int o=0;o<32;o++){
            float a = sw[B11+o];
            #pragma unroll
            for (int c=0;c<32;c++) a += h1[c]*sw[W11+o*32+c];
            h2[o] = fmaxf(a,0.f);
        }
        float h3[64];
        #pragma unroll
        for (int o=0;o<64;o++){
            float a = sw[B12+o];
            #pragma unroll
            for (int c=0;c<32;c++) a += h2[c]*sw[W12+o*32+c];
            h3[o] = fmaxf(a,0.f);
        }
        #pragma unroll
        for (int s=1;s<32;s<<=1){
            #pragma unroll
            for (int c=0;c<64;c++) h3[c] = fmaxf(h3[c], __shfl_xor(h3[c], s));
        }
        if (lane==0){
            #pragma unroll
            for (int c=0;c<64;c++) fo[35+c]=h3[c];
        }
    }
}

/* ---------------- K3: per-box stable top-k + gather + write ------------- */
__global__ void k_sample(const float4* __restrict__ spk, const float2* __restrict__ epk,
                         const float* __restrict__ feats,
                         const float* __restrict__ rois, float* __restrict__ out)
{
    int id = blockIdx.x;           /* 0..1023 : (f, m) */
    int f = id >> 7, m = id & 127;
    int lane = threadIdx.x;
    const float* bp = rois + (size_t)(f*NBOX+m)*7;
    float bx=bp[0], by=bp[1], dx=bp[3], dy=bp[4];
    float hx=__fmul_rn(dx,0.5f), hy=__fmul_rn(dy,0.5f);
    float hd=sqrtf(__fadd_rn(__fmul_rn(hx,hx),__fmul_rn(hy,hy)));
    float rr=__fmul_rn(hd,1.1f);

    __shared__ int lt[32], lf[32];
    int cT=0, cF=0;
    const float4* fsp = spk + f*NPTS;
    uint64_t below = (1ull<<lane)-1ull;
    for (int j0=0;j0<NPTS;j0+=64){
        int j=j0+lane;
        float4 q = fsp[j];
        float ddx=__fsub_rn(bx,q.x), ddy=__fsub_rn(by,q.y);
        float dis=sqrtf(__fadd_rn(__fmul_rn(ddx,ddx),__fmul_rn(ddy,ddy)));
        bool pm = (dis <= rr) && (q.w > 0.5f);
        uint64_t mT=__ballot(pm), mF=~mT;
        if (pm){ int pos=cT+__popcll(mT&below); if (pos<32) lt[pos]=j; }
        else   { int pos=cF+__popcll(mF&below); if (pos<32) lf[pos]=j; }
        cT += __popcll(mT); cF += 64-__popcll(mT);
        if (cT>=32 && cF>=32) break;
    }
    __syncthreads();
    cT = min(cT,32);
    if (lane < 32){
        int s = lane;
        bool masked = s < cT;
        int idx = masked ? lt[s] : lf[s-cT];
        float mk = masked ? 1.f : 0.f;
        int b = f >> 2, t = f & 3;
        size_t row = (((size_t)(b*NBOX+m))*TT + t)*NS + s;
        float4 q = fsp[idx]; float2 e = epk[f*NPTS+idx];
        float* o0 = out + row*5;
        o0[0]=q.x*mk; o0[1]=q.y*mk; o0[2]=q.z*mk; o0[3]=e.x*mk; o0[4]=e.y*mk;
        const float* fi = feats + (size_t)(f*NPTS+idx)*FEATC;
        float* o1 = out + OUT1OFF + row*FEATC;
        for (int c=0;c<FEATC;c++) o1[c]=fi[c];
    }
}

extern "C" void kernel_launch(void* const* d_in, const int* in_sizes, int n_in,
                              void* d_out, int out_size, void* d_ws, size_t ws_size,
                              hipStream_t stream)
{
    const float* pts  = (const float*)d_in[0];
    const float* rois = (const float*)d_in[1];
    const float* w00=(const float*)d_in[2],  *b00=(const float*)d_in[3];
    const float* w01=(const float*)d_in[4],  *b01=(const float*)d_in[5];
    const float* w02=(const float*)d_in[6],  *b02=(const float*)d_in[7];
    const float* w10=(const float*)d_in[8],  *b10=(const float*)d_in[9];
    const float* w11=(const float*)d_in[10], *b11=(const float*)d_in[11];
    const float* w12=(const float*)d_in[12], *b12=(const float*)d_in[13];
    float* out = (float*)d_out;

    char* ws = (char*)d_ws;
    float4* spk  = (float4*)ws;                         /* 8*4096*16 = 524288 B  */
    float2* epk  = (float2*)(ws + 524288);              /* 8*4096*8  = 262144 B  */
    float*  feats= (float*) (ws + 786432);              /* 8*4096*99*4 = 12.98 MB */

    hipLaunchKernelGGL(k_prep,  dim3(NFRM*16), dim3(256), 0, stream, pts, rois, spk, epk);
    hipLaunchKernelGGL(k_feats, dim3(NFRM*NPTS/4), dim3(256), 0, stream,
                       spk, epk, feats, w00,b00,w01,b01,w02,b02,w10,b10,w11,b11,w12,b12);
    hipLaunchKernelGGL(k_sample, dim3(NFRM*NBOX), dim3(64), 0, stream,
                       spk, epk, feats, rois, out);
}

// Round 4
// 179.767 us; speedup vs baseline: 3.3079x; 3.3079x over previous
//
#include <hip/hip_runtime.h>
#include <hip/hip_bf16.h>
#include <stdint.h>

#define NFRM 8
#define NPTS 4096
#define NBOX 128
#define NS   32
#define TT   4
#define BB   2
#define FEATC 99
#define OUT1OFF (BB*NBOX*TT*NS*5)   /* 163840 */

/* ---- workspace layout (bytes) ---- */
#define WS_SPK   0u
#define WS_EPK   524288u
#define WS_FEATS 786432u
#define WS_SIDX  13762560u
#define WS_SCNT  13893632u
#define WS_FLAGS 13897728u
#define WS_NCNT  14028800u
#define WS_NLST  14028832u
/* end ~14.16 MB */

/* ---------------- K1: validity + packed f32 point arrays ---------------- */
__global__ void k_prep(const float* __restrict__ pts, const float* __restrict__ rois,
                       float4* __restrict__ spk, float2* __restrict__ epk)
{
    int f = blockIdx.x >> 4;
    int n = ((blockIdx.x & 15) << 8) | threadIdx.x;
    __shared__ float bqx[NBOX], bqy[NBOX], brv[NBOX];
    if (threadIdx.x < NBOX){
        const float* bp = rois + (size_t)(f*NBOX + threadIdx.x)*7;
        float bx=bp[0], by=bp[1], dx=bp[3], dy=bp[4];
        float hx=__fmul_rn(dx,0.5f), hy=__fmul_rn(dy,0.5f);
        float hd=sqrtf(__fadd_rn(__fmul_rn(hx,hx),__fmul_rn(hy,hy)));
        brv[threadIdx.x]=ceilf(__fdiv_rn(__fmul_rn(hd,1.1f),0.4f));
        bqx[threadIdx.x]=floorf(__fdiv_rn(__fsub_rn(bx,-75.2f),0.4f));
        bqy[threadIdx.x]=floorf(__fdiv_rn(__fsub_rn(by,-75.2f),0.4f));
    }
    __syncthreads();
    const float* pp = pts + (size_t)(f*NPTS+n)*5;
    float x=pp[0], y=pp[1], z=pp[2], it=pp[3], ts=pp[4];
    float cx=floorf(__fdiv_rn(__fsub_rn(x,-75.2f),0.4f));
    float cy=floorf(__fdiv_rn(__fsub_rn(y,-75.2f),0.4f));
    float v=0.f;
    for (int m=0;m<NBOX;m++)
        if (fabsf(bqx[m]-cx)<brv[m] && fabsf(bqy[m]-cy)<brv[m]){ v=1.f; break; }
    spk[f*NPTS+n]=make_float4(x,y,z,v);
    epk[f*NPTS+n]=make_float2(it,ts);
}

/* ---------------- K2: per-box stable top-k -> out0, sidx, flags --------- */
__global__ void k_select(const float4* __restrict__ spk, const float2* __restrict__ epk,
                         const float* __restrict__ rois, float* __restrict__ out,
                         int* __restrict__ sidx, int* __restrict__ scnt,
                         int* __restrict__ flags)
{
    int id = blockIdx.x;           /* 0..1023 : (f, m) */
    int f = id >> 7, m = id & 127;
    int lane = threadIdx.x;
    const float* bp = rois + (size_t)(f*NBOX+m)*7;
    float bx=bp[0], by=bp[1], dx=bp[3], dy=bp[4];
    float hx=__fmul_rn(dx,0.5f), hy=__fmul_rn(dy,0.5f);
    float hd=sqrtf(__fadd_rn(__fmul_rn(hx,hx),__fmul_rn(hy,hy)));
    float rr=__fmul_rn(hd,1.1f);

    __shared__ int lt[32], lf[32];
    int cT=0, cF=0;
    const float4* fsp = spk + f*NPTS;
    uint64_t below = (1ull<<lane)-1ull;
    for (int j0=0;j0<NPTS;j0+=64){
        int j=j0+lane;
        float4 q = fsp[j];
        float ddx=__fsub_rn(bx,q.x), ddy=__fsub_rn(by,q.y);
        float dis=sqrtf(__fadd_rn(__fmul_rn(ddx,ddx),__fmul_rn(ddy,ddy)));
        bool pm = (dis <= rr) && (q.w > 0.5f);
        uint64_t mT=__ballot(pm), mF=~mT;
        if (pm){ int pos=cT+__popcll(mT&below); if (pos<32) lt[pos]=j; }
        else   { int pos=cF+__popcll(mF&below); if (pos<32) lf[pos]=j; }
        cT += __popcll(mT); cF += 64-__popcll(mT);
        if (cT>=32 && cF>=32) break;
    }
    __syncthreads();
    cT = min(cT,32);
    if (lane==0) scnt[f*NBOX+m]=cT;
    if (lane < 32){
        int s = lane;
        bool masked = s < cT;
        int idx = masked ? lt[s] : lf[s-cT];
        float mk = masked ? 1.f : 0.f;
        sidx[(f*NBOX+m)*NS+s]=idx;
        flags[f*NPTS+idx]=1;
        int b = f >> 2, t = f & 3;
        size_t row = (((size_t)(b*NBOX+m))*TT + t)*NS + s;
        float4 q = fsp[idx]; float2 e = epk[f*NPTS+idx];
        float* o0 = out + row*5;
        o0[0]=q.x*mk; o0[1]=q.y*mk; o0[2]=q.z*mk; o0[3]=e.x*mk; o0[4]=e.y*mk;
    }
}

/* ---------------- K3: compact flagged points per frame ------------------ */
__global__ void k_compact(const int* __restrict__ flags, int* __restrict__ ncount,
                          int* __restrict__ needlist)
{
    int f = blockIdx.x;
    for (int i = threadIdx.x; i < NPTS; i += blockDim.x){
        if (flags[f*NPTS+i]){
            int pos = atomicAdd(&ncount[f], 1);
            needlist[f*NPTS+pos] = i;
        }
    }
}

/* ---------------- K4: lazy ball-group + MLP + maxpool ------------------- */
/* LDS weight layout offsets (floats) */
#define W00 0
#define B00 80
#define W01 96
#define B01 352
#define W02 368
#define B02 880
#define W10 912
#define B10 1072
#define W11 1104
#define B11 2128
#define W12 2160
#define B12 4208
#define SWTOT 4272

__global__ __launch_bounds__(256) void k_feats_lazy(
    const float4* __restrict__ spk, const float2* __restrict__ epk,
    float* __restrict__ feats,
    const int* __restrict__ ncount, const int* __restrict__ needlist,
    const float* __restrict__ w00,const float* __restrict__ b00,
    const float* __restrict__ w01,const float* __restrict__ b01,
    const float* __restrict__ w02,const float* __restrict__ b02,
    const float* __restrict__ w10,const float* __restrict__ b10,
    const float* __restrict__ w11,const float* __restrict__ b11,
    const float* __restrict__ w12,const float* __restrict__ b12)
{
    int f = blockIdx.x >> 10;
    int base4 = (blockIdx.x & 1023) << 2;
    int cnt = ncount[f];
    if (base4 >= cnt) return;

    __shared__ float sw[SWTOT];
    __shared__ int   lists[4][48];
    int tid = threadIdx.x;
    {
        const float* srcs[12] = {w00,b00,w01,b01,w02,b02,w10,b10,w11,b11,w12,b12};
        const int offs[12]   = {W00,B00,W01,B01,W02,B02,W10,B10,W11,B11,W12,B12};
        const int cnts[12]   = {80,16,256,16,512,32,160,32,1024,32,2048,64};
        for (int a=0;a<12;a++)
            for (int i=tid;i<cnts[a];i+=256) sw[offs[a]+i]=srcs[a][i];
    }
    __syncthreads();

    int wv = tid >> 6, lane = tid & 63;
    int li = min(base4 + wv, cnt-1);
    int n = needlist[f*NPTS + li];
    const float4* fsp = spk + f*NPTS;
    const float2* fep = epk + f*NPTS;
    float4 me = fsp[n];
    float sa = __fadd_rn(__fadd_rn(__fmul_rn(me.x,me.x),__fmul_rn(me.y,me.y)),__fmul_rn(me.z,me.z));
    const float RR1 = (float)(0.8*0.8);
    const float RR2 = (float)(1.6*1.6);
    int cnt1=0, cnt2=0;
    int* l1 = lists[wv];
    int* l2 = lists[wv]+16;
    uint64_t below = (1ull<<lane)-1ull;
    for (int j0=0;j0<NPTS;j0+=64){
        int j = j0 + lane;
        float4 q = fsp[j];
        float sb  = __fadd_rn(__fadd_rn(__fmul_rn(q.x,q.x),__fmul_rn(q.y,q.y)),__fmul_rn(q.z,q.z));
        float dot = __fadd_rn(__fadd_rn(__fmul_rn(me.x,q.x),__fmul_rn(me.y,q.y)),__fmul_rn(me.z,q.z));
        float d2 = fmaxf(__fsub_rn(__fadd_rn(sa,sb),__fmul_rn(2.0f,dot)), 0.f);
        bool vj = q.w > 0.5f;
        bool p1 = (d2 < RR1) && vj;
        bool p2 = (d2 < RR2) && vj;
        uint64_t m1 = __ballot(p1), m2 = __ballot(p2);
        if (p1){ int pos = cnt1 + __popcll(m1 & below); if (pos < 16) l1[pos] = j; }
        if (p2){ int pos = cnt2 + __popcll(m2 & below); if (pos < 32) l2[pos] = j; }
        cnt1 += __popcll(m1); cnt2 += __popcll(m2);
        if (cnt1 >= 16 && cnt2 >= 32) break;
    }
    cnt1 = min(cnt1,16); cnt2 = min(cnt2,32);

    float* fo = feats + (size_t)(f*NPTS+n)*FEATC;

    /* ---- MLP0: 16 neighbors, 5->16->16->32, maxpool ---- */
    {
        int k = lane & 15;
        int idx = (k < cnt1) ? l1[k] : ((cnt1>0) ? l1[0] : 0);
        float4 q = fsp[idx]; float2 e = fep[idx];
        float g0=__fsub_rn(q.x,me.x), g1=__fsub_rn(q.y,me.y), g2=__fsub_rn(q.z,me.z);
        float g3=e.x, g4=e.y;
        float h1[16];
        #pragma unroll
        for (int o=0;o<16;o++){
            float a = sw[B00+o];
            a += g0*sw[W00+o*5+0]; a += g1*sw[W00+o*5+1]; a += g2*sw[W00+o*5+2];
            a += g3*sw[W00+o*5+3]; a += g4*sw[W00+o*5+4];
            h1[o] = fmaxf(a,0.f);
        }
        float h2[16];
        #pragma unroll
        for (int o=0;o<16;o++){
            float a = sw[B01+o];
            #pragma unroll
            for (int c=0;c<16;c++) a += h1[c]*sw[W01+o*16+c];
            h2[o] = fmaxf(a,0.f);
        }
        float h3[32];
        #pragma unroll
        for (int o=0;o<32;o++){
            float a = sw[B02+o];
            #pragma unroll
            for (int c=0;c<16;c++) a += h2[c]*sw[W02+o*16+c];
            h3[o] = fmaxf(a,0.f);
        }
        #pragma unroll
        for (int s=1;s<16;s<<=1){
            #pragma unroll
            for (int c=0;c<32;c++) h3[c] = fmaxf(h3[c], __shfl_xor(h3[c], s));
        }
        if (lane==0){
            fo[0]=me.x; fo[1]=me.y; fo[2]=me.z;
            #pragma unroll
            for (int c=0;c<32;c++) fo[3+c]=h3[c];
        }
    }

    /* ---- MLP1: 32 neighbors, 5->32->32->64, maxpool ---- */
    {
        int k = lane & 31;
        int idx = (k < cnt2) ? l2[k] : ((cnt2>0) ? l2[0] : 0);
        float4 q = fsp[idx]; float2 e = fep[idx];
        float g0=__fsub_rn(q.x,me.x), g1=__fsub_rn(q.y,me.y), g2=__fsub_rn(q.z,me.z);
        float g3=e.x, g4=e.y;
        float h1[32];
        #pragma unroll
        for (int o=0;o<32;o++){
            float a = sw[B10+o];
            a += g0*sw[W10+o*5+0]; a += g1*sw[W10+o*5+1]; a += g2*sw[W10+o*5+2];
            a += g3*sw[W10+o*5+3]; a += g4*sw[W10+o*5+4];
            h1[o] = fmaxf(a,0.f);
        }
        float h2[32];
        #pragma unroll
        for (int o=0;o<32;o++){
            float a = sw[B11+o];
            #pragma unroll
            for (int c=0;c<32;c++) a += h1[c]*sw[W11+o*32+c];
            h2[o] = fmaxf(a,0.f);
        }
        float h3[64];
        #pragma unroll
        for (int o=0;o<64;o++){
            float a = sw[B12+o];
            #pragma unroll
            for (int c=0;c<32;c++) a += h2[c]*sw[W12+o*32+c];
            h3[o] = fmaxf(a,0.f);
        }
        #pragma unroll
        for (int s=1;s<32;s<<=1){
            #pragma unroll
            for (int c=0;c<64;c++) h3[c] = fmaxf(h3[c], __shfl_xor(h3[c], s));
        }
        if (lane==0){
            #pragma unroll
            for (int c=0;c<64;c++) fo[35+c]=h3[c];
        }
    }
}

/* ---------------- K5: gather feats rows -> out1 ------------------------- */
__global__ void k_gather(const float* __restrict__ feats, const int* __restrict__ sidx,
                         float* __restrict__ out)
{
    int id = blockIdx.x;           /* 0..1023 : (f, m) */
    int f = id >> 7, m = id & 127;
    int tid = threadIdx.x;
    int s = tid >> 3, j = tid & 7;
    int idx = sidx[(f*NBOX+m)*NS+s];
    int b = f >> 2, t = f & 3;
    size_t row = (((size_t)(b*NBOX+m))*TT + t)*NS + s;
    const float* fi = feats + (size_t)(f*NPTS+idx)*FEATC;
    float* o1 = out + OUT1OFF + row*FEATC;
    for (int c=j; c<FEATC; c+=8) o1[c]=fi[c];
}

extern "C" void kernel_launch(void* const* d_in, const int* in_sizes, int n_in,
                              void* d_out, int out_size, void* d_ws, size_t ws_size,
                              hipStream_t stream)
{
    const float* pts  = (const float*)d_in[0];
    const float* rois = (const float*)d_in[1];
    const float* w00=(const float*)d_in[2],  *b00=(const float*)d_in[3];
    const float* w01=(const float*)d_in[4],  *b01=(const float*)d_in[5];
    const float* w02=(const float*)d_in[6],  *b02=(const float*)d_in[7];
    const float* w10=(const float*)d_in[8],  *b10=(const float*)d_in[9];
    const float* w11=(const float*)d_in[10], *b11=(const float*)d_in[11];
    const float* w12=(const float*)d_in[12], *b12=(const float*)d_in[13];
    float* out = (float*)d_out;

    char* ws = (char*)d_ws;
    float4* spk   = (float4*)(ws + WS_SPK);
    float2* epk   = (float2*)(ws + WS_EPK);
    float*  feats = (float*) (ws + WS_FEATS);
    int*    sidx  = (int*)   (ws + WS_SIDX);
    int*    scnt  = (int*)   (ws + WS_SCNT);
    int*    flags = (int*)   (ws + WS_FLAGS);
    int*    ncnt  = (int*)   (ws + WS_NCNT);
    int*    nlst  = (int*)   (ws + WS_NLST);

    /* zero flags + ncount each launch (contiguous region) */
    hipMemsetAsync(ws + WS_FLAGS, 0, (WS_NCNT - WS_FLAGS) + 32, stream);

    hipLaunchKernelGGL(k_prep,   dim3(NFRM*16), dim3(256), 0, stream, pts, rois, spk, epk);
    hipLaunchKernelGGL(k_select, dim3(NFRM*NBOX), dim3(64), 0, stream,
                       spk, epk, rois, out, sidx, scnt, flags);
    hipLaunchKernelGGL(k_compact, dim3(NFRM), dim3(256), 0, stream, flags, ncnt, nlst);
    hipLaunchKernelGGL(k_feats_lazy, dim3(NFRM*1024), dim3(256), 0, stream,
                       spk, epk, feats, ncnt, nlst,
                       w00,b00,w01,b01,w02,b02,w10,b10,w11,b11,w12,b12);
    hipLaunchKernelGGL(k_gather, dim3(NFRM*NBOX), dim3(256), 0, stream,
                       feats, sidx, out);
}